// Round 8
// baseline (1060.587 us; speedup 1.0000x reference)
//
#include <hip/hip_runtime.h>

#define KBINS  10
#define SBIN   100
#define BETA   0.9f
#define THR    1.0f
#define CDIV(a,b) (((a)+(b)-1)/(b))

// Padded spike layouts (halo zeros: 1 row top/bottom, 1 col left, 7 right):
//   spk1p [1000][ 4][52][192]   spk2p [1000][ 8][27][100]   spk3p [1000][16][15][54]

// ---------------------------------------------------------------------------
__global__ void k_zero16(float4* __restrict__ p, int n16) {
    int i = blockIdx.x * blockDim.x + threadIdx.x;
    if (i < n16) p[i] = make_float4(0.f, 0.f, 0.f, 0.f);
}

// ---------------------------------------------------------------------------
// Layer-1 conv, full T: 4 outputs (w) per thread, 4 couts.
// x [1000][100][368] -> c1 [1000][4][50][184]. pad_lo=(0,0).
// ---------------------------------------------------------------------------
__global__ void k_conv1(const float* __restrict__ x,
                        const float* __restrict__ w1,
                        const float* __restrict__ b1,
                        float* __restrict__ c1) {
    int n = blockIdx.x * blockDim.x + threadIdx.x;
    if (n >= 1000 * 50 * 46) return;
    int wq  = n % 46;
    int tmp = n / 46;
    int h   = tmp % 50;
    int t   = tmp / 50;
    int w0  = wq * 4;

    const float* xt = x + (size_t)t * 36800;
    float rm2 = (h  < 49)  ? 1.f : 0.f;
    float cm8 = (w0 < 180) ? 1.f : 0.f;
    int   r2  = min(2 * h + 2, 99);
    int   cb  = 2 * w0;
    int   c8  = min(cb + 8, 367);

    const float* row0 = xt + (2 * h) * 368 + cb;
    const float* row1 = row0 + 368;
    const float* row2 = xt + r2 * 368 + cb;

    float tap[3][9];
    #pragma unroll
    for (int j = 0; j < 8; j++) {
        tap[0][j] = row0[j];
        tap[1][j] = row1[j];
        tap[2][j] = row2[j] * rm2;
    }
    tap[0][8] = xt[(2 * h) * 368 + c8] * cm8;
    tap[1][8] = xt[(2 * h + 1) * 368 + c8] * cm8;
    tap[2][8] = xt[r2 * 368 + c8] * (rm2 * cm8);

    float* ot = c1 + (size_t)t * 36800 + h * 184 + w0;
    #pragma unroll
    for (int co = 0; co < 4; co++) {
        float b = b1[co];
        float a0 = b, a1 = b, a2 = b, a3 = b;
        #pragma unroll
        for (int r = 0; r < 3; r++) {
            #pragma unroll
            for (int kw = 0; kw < 3; kw++) {
                float wv = w1[co * 9 + r * 3 + kw];
                a0 = fmaf(tap[r][0 + kw], wv, a0);
                a1 = fmaf(tap[r][2 + kw], wv, a1);
                a2 = fmaf(tap[r][4 + kw], wv, a2);
                a3 = fmaf(tap[r][6 + kw], wv, a3);
            }
        }
        *(float4*)(ot + (size_t)co * 9200) = make_float4(a0, a1, a2, a3);
    }
}

// ---------------------------------------------------------------------------
// Membrane scan, full 1000 steps, PF=20 register double-buffer.
// Reads cbuf [1000][C][HW]; writes padded u8 spikes + per-bin mean/std.
// ---------------------------------------------------------------------------
__global__ void k_scan(const float* __restrict__ cbuf,
                       unsigned char* __restrict__ spk,
                       float* __restrict__ skip,
                       float* __restrict__ mscratch,
                       int C, int HW, int Win, int Wp, int HpWp, int write_spk) {
    const int PF = 20;
    int CHW = C * HW;
    int p = blockIdx.x * blockDim.x + threadIdx.x;
    if (p >= CHW) return;
    int c  = p / HW;
    int hw = p - c * HW;
    int h  = hw / Win, w = hw - h * Win;

    const size_t tstr = (size_t)C * HpWp;
    unsigned char* sp = spk + (size_t)c * HpWp + (h + 1) * Wp + (w + 1);

    float m = 0.0f;
    float va[PF], vb[PF];
    #pragma unroll
    for (int j = 0; j < PF; j++) va[j] = cbuf[(size_t)j * CHW + p];

    const int T = KBINS * SBIN;
    for (int k = 0; k < KBINS; k++) {
        float s = 0.0f, q = 0.0f;
        for (int b = 0; b < SBIN / PF; b++) {
            int t0 = k * SBIN + b * PF;
            int tn = t0 + PF;
            bool more = (tn < T);
            #pragma unroll
            for (int j = 0; j < PF; j++)
                vb[j] = more ? cbuf[(size_t)(tn + j) * CHW + p] : 0.0f;
            #pragma unroll
            for (int j = 0; j < PF; j++) {
                m = fmaf(m, BETA, va[j]);
                float spv = (m - THR > 0.0f) ? 1.0f : 0.0f;
                m -= spv * THR;
                if (write_spk) sp[(size_t)(t0 + j) * tstr] = (unsigned char)spv;
                s += m;
                q = fmaf(m, m, q);
            }
            #pragma unroll
            for (int j = 0; j < PF; j++) va[j] = vb[j];
        }
        float mean = s * (1.0f / SBIN);
        float var  = q * (1.0f / SBIN) - mean * mean;
        float sd   = sqrtf(fmaxf(var, 1e-8f));
        skip[(size_t)(k * 2 * C + c) * HW + hw]     = mean;
        skip[(size_t)(k * 2 * C + C + c) * HW + hw] = sd;
    }
    mscratch[p] = m;   // keep the compiler honest; buffer is scratch
}

// ---------------------------------------------------------------------------
// Stride-2 time-conv from padded u8 spikes, OW outputs/thread, COG couts.
// Branch-free taps (halo zeros). Vectorized stores. Full T.
// ---------------------------------------------------------------------------
template<int CIN, int COUT, int COG, int OW,
         int HOUT, int WOUT, int PADH, int HP, int WP>
__global__ void k_convs2(const unsigned char* __restrict__ spk,
                         const float* __restrict__ wt,
                         const float* __restrict__ bias,
                         float* __restrict__ out) {
    const int WQ = (WOUT + OW - 1) / OW;
    const int NT = 2 * OW + 1;
    int n = blockIdx.x * blockDim.x + threadIdx.x;
    if (n >= 1000 * HOUT * WQ) return;
    int wq  = n % WQ;
    int tmp = n / WQ;
    int h   = tmp % HOUT;
    int t   = tmp / HOUT;
    int cog = blockIdx.y;
    int w0  = wq * OW;

    const unsigned char* base = spk + (size_t)t * CIN * HP * WP
                              + (2 * h - PADH + 1) * WP + (2 * w0 + 1);

    float acc[OW][COG];
    #pragma unroll
    for (int q = 0; q < OW; q++)
        #pragma unroll
        for (int co = 0; co < COG; co++) acc[q][co] = bias[cog * COG + co];

    for (int ci = 0; ci < CIN; ci++) {
        const unsigned char* ic = base + (size_t)ci * HP * WP;
        float tap[3][NT];
        #pragma unroll
        for (int r = 0; r < 3; r++)
            #pragma unroll
            for (int j = 0; j < NT; j++)
                tap[r][j] = (float)ic[r * WP + j];
        #pragma unroll
        for (int co = 0; co < COG; co++) {
            const float* wc = wt + ((size_t)(cog * COG + co) * CIN + ci) * 9;
            #pragma unroll
            for (int r = 0; r < 3; r++)
                #pragma unroll
                for (int kw = 0; kw < 3; kw++) {
                    float wv = wc[r * 3 + kw];
                    #pragma unroll
                    for (int q = 0; q < OW; q++)
                        acc[q][co] = fmaf(tap[r][2 * q + kw], wv, acc[q][co]);
                }
        }
    }

    float* ot = out + ((size_t)t * COUT + cog * COG) * (HOUT * WOUT) + h * WOUT + w0;
    #pragma unroll
    for (int co = 0; co < COG; co++) {
        float* oc = ot + (size_t)co * (HOUT * WOUT);
        if constexpr (OW == 4) {
            *(float4*)oc = make_float4(acc[0][co], acc[1][co], acc[2][co], acc[3][co]);
        } else {
            if (w0 + 2 <= WOUT) *(float2*)oc = make_float2(acc[0][co], acc[1][co]);
            else                oc[0] = acc[0][co];
        }
    }
}

// ---------------------------------------------------------------------------
// Decoder level 4: split-K conv, atomic accumulate into pre-act d4.
// chunk 0 adds bias. Consumer applies ReLU.
// ---------------------------------------------------------------------------
__global__ void k_dec_conv0(const float* __restrict__ in, int Cin, int H, int W,
                            const float* __restrict__ wt,
                            const float* __restrict__ bias,
                            float* __restrict__ dout,
                            int Cout, int CS) {
    int HW  = H * W;
    int pix = blockIdx.x * blockDim.x + threadIdx.x;
    if (pix >= HW) return;
    int co    = blockIdx.y;
    int chunk = blockIdx.z;
    int h = pix / W, w = pix - h * W;

    int off[9]; float msk[9];
    #pragma unroll
    for (int kh = 0; kh < 3; kh++) {
        int r = h + kh - 1;
        bool rok = (r >= 0) && (r < H);
        int rc = rok ? r : 0;
        #pragma unroll
        for (int kw = 0; kw < 3; kw++) {
            int cc = w + kw - 1;
            bool cok = (cc >= 0) && (cc < W);
            int ccc = cok ? cc : 0;
            off[kh * 3 + kw] = rc * W + ccc;
            msk[kh * 3 + kw] = (rok && cok) ? 1.0f : 0.0f;
        }
    }

    const float* ibase = in + (size_t)chunk * CS * HW;
    const float* wbase = wt + ((size_t)co * Cin + (size_t)chunk * CS) * 9;
    float acc0 = (chunk == 0) ? bias[co] : 0.0f;
    float acc1 = 0.0f;
    for (int ci = 0; ci < CS; ci += 2) {
        const float* ic0 = ibase + (size_t)ci * HW;
        const float* wc0 = wbase + ci * 9;
        #pragma unroll
        for (int j = 0; j < 9; j++)
            acc0 = fmaf(msk[j] * ic0[off[j]], wc0[j], acc0);
        const float* ic1 = ic0 + HW;
        const float* wc1 = wc0 + 9;
        #pragma unroll
        for (int j = 0; j < 9; j++)
            acc1 = fmaf(msk[j] * ic1[off[j]], wc1[j], acc1);
    }
    atomicAdd(&dout[(size_t)co * HW + pix], acc0 + acc1);
}

// ---------------------------------------------------------------------------
// Decoder levels 3-1: conv with FUSED bilinear upsample of relu(dprev).
// Channels [0,Cup) sampled from pre-act dprev (ReLU on load); [Cup,Cin) from
// skip. Split-K atomic accumulate into pre-act dout; chunk 0 adds bias.
// ---------------------------------------------------------------------------
__global__ void k_dec_conv(const float* __restrict__ skp, int Cskip,
                           const float* __restrict__ dprev, int Cup,
                           int Hi, int Wi,
                           const float* __restrict__ wt,
                           const float* __restrict__ bias,
                           float* __restrict__ dout,
                           int Cout, int CS, int H, int W) {
    int HW  = H * W;
    int pix = blockIdx.x * blockDim.x + threadIdx.x;
    if (pix >= HW) return;
    int co    = blockIdx.y;
    int chunk = blockIdx.z;
    int h = pix / W, w = pix - h * W;
    int Cin = Cup + Cskip;

    int roff[3], h0c[3], h1c[3];
    float rmsk[3], ah[3];
    #pragma unroll
    for (int kh = 0; kh < 3; kh++) {
        int r = h + kh - 1;
        bool rok = (r >= 0) && (r < H);
        roff[kh] = rok ? r : 0;
        rmsk[kh] = rok ? 1.0f : 0.0f;
        float ph = (r + 0.5f) * (float)Hi / (float)H - 0.5f;
        float fh = floorf(ph);
        ah[kh] = ph - fh;
        int hh = (int)fh;
        h0c[kh] = min(max(hh, 0), Hi - 1);
        h1c[kh] = min(max(hh + 1, 0), Hi - 1);
    }
    int coff[3], w0c[3], w1c[3];
    float cmsk[3], aw[3];
    #pragma unroll
    for (int kw = 0; kw < 3; kw++) {
        int cc = w + kw - 1;
        bool cok = (cc >= 0) && (cc < W);
        coff[kw] = cok ? cc : 0;
        cmsk[kw] = cok ? 1.0f : 0.0f;
        float pw = (cc + 0.5f) * (float)Wi / (float)W - 0.5f;
        float fw = floorf(pw);
        aw[kw] = pw - fw;
        int ww = (int)fw;
        w0c[kw] = min(max(ww, 0), Wi - 1);
        w1c[kw] = min(max(ww + 1, 0), Wi - 1);
    }

    float acc0 = (chunk == 0) ? bias[co] : 0.0f;
    float acc1 = 0.0f;
    for (int cl = 0; cl < CS; cl++) {
        int ci = chunk * CS + cl;
        const float* wc = wt + ((size_t)co * Cin + ci) * 9;
        float a = 0.0f;
        if (ci < Cup) {
            const float* dc = dprev + (size_t)ci * Hi * Wi;
            #pragma unroll
            for (int kh = 0; kh < 3; kh++) {
                #pragma unroll
                for (int kw = 0; kw < 3; kw++) {
                    float v00 = fmaxf(dc[h0c[kh] * Wi + w0c[kw]], 0.0f);
                    float v01 = fmaxf(dc[h0c[kh] * Wi + w1c[kw]], 0.0f);
                    float v10 = fmaxf(dc[h1c[kh] * Wi + w0c[kw]], 0.0f);
                    float v11 = fmaxf(dc[h1c[kh] * Wi + w1c[kw]], 0.0f);
                    float v = (1.0f - ah[kh]) * ((1.0f - aw[kw]) * v00 + aw[kw] * v01)
                            + ah[kh] * ((1.0f - aw[kw]) * v10 + aw[kw] * v11);
                    a = fmaf(v * rmsk[kh] * cmsk[kw], wc[kh * 3 + kw], a);
                }
            }
        } else {
            const float* ic = skp + (size_t)(ci - Cup) * HW;
            #pragma unroll
            for (int kh = 0; kh < 3; kh++)
                #pragma unroll
                for (int kw = 0; kw < 3; kw++)
                    a = fmaf(rmsk[kh] * cmsk[kw] * ic[roff[kh] * W + coff[kw]],
                             wc[kh * 3 + kw], a);
        }
        if (cl & 1) acc1 += a; else acc0 += a;
    }
    atomicAdd(&dout[(size_t)co * HW + pix], acc0 + acc1);
}

// ---------------------------------------------------------------------------
// Final: bilinear up relu(d1) [8,50,184] -> (100,368), fused 1x1 conv.
// ---------------------------------------------------------------------------
__global__ void k_final(const float* __restrict__ d1,
                        const float* __restrict__ wo,
                        const float* __restrict__ bo,
                        float* __restrict__ out) {
    int n = blockIdx.x * blockDim.x + threadIdx.x;
    if (n >= 36800) return;
    int w = n % 368, h = n / 368;
    float ph = (h + 0.5f) * 0.5f - 0.5f;
    float pw = (w + 0.5f) * 0.5f - 0.5f;
    float fh = floorf(ph), fw = floorf(pw);
    int h0 = (int)fh, w0 = (int)fw;
    float ah = ph - fh, aw = pw - fw;
    int h0c = min(max(h0, 0), 49),  h1c = min(max(h0 + 1, 0), 49);
    int w0c = min(max(w0, 0), 183), w1c = min(max(w0 + 1, 0), 183);
    float acc = bo[0];
    #pragma unroll
    for (int c = 0; c < 8; c++) {
        const float* sc = d1 + c * 9200;
        float v00 = fmaxf(sc[h0c * 184 + w0c], 0.0f);
        float v01 = fmaxf(sc[h0c * 184 + w1c], 0.0f);
        float v10 = fmaxf(sc[h1c * 184 + w0c], 0.0f);
        float v11 = fmaxf(sc[h1c * 184 + w1c], 0.0f);
        float v = (1.0f - ah) * ((1.0f - aw) * v00 + aw * v01)
                + ah * ((1.0f - aw) * v10 + aw * v11);
        acc = fmaf(wo[c], v, acc);
    }
    out[n] = acc;
}

// ---------------------------------------------------------------------------
extern "C" void kernel_launch(void* const* d_in, const int* in_sizes, int n_in,
                              void* d_out, int out_size, void* d_ws, size_t ws_size,
                              hipStream_t stream) {
    (void)in_sizes; (void)n_in; (void)out_size; (void)ws_size;
    const float* x   = (const float*)d_in[0];
    const float* w1  = (const float*)d_in[1];
    const float* b1  = (const float*)d_in[2];
    const float* w2  = (const float*)d_in[3];
    const float* b2  = (const float*)d_in[4];
    const float* w3  = (const float*)d_in[5];
    const float* b3  = (const float*)d_in[6];
    const float* w4  = (const float*)d_in[7];
    const float* b4  = (const float*)d_in[8];
    const float* dw4 = (const float*)d_in[9];
    const float* db4 = (const float*)d_in[10];
    const float* dw3 = (const float*)d_in[11];
    const float* db3 = (const float*)d_in[12];
    const float* dw2 = (const float*)d_in[13];
    const float* db2 = (const float*)d_in[14];
    const float* dw1 = (const float*)d_in[15];
    const float* db1 = (const float*)d_in[16];
    const float* wo  = (const float*)d_in[17];
    const float* bo  = (const float*)d_in[18];
    float* out = (float*)d_out;

    // ---- workspace (~228 MB); spike buffers + decoder accumulators are
    //      allocated CONTIGUOUSLY so one zero kernel covers them all ----
    char* ws = (char*)d_ws;
    size_t off = 0;
    auto alloc = [&](size_t bytes) -> void* {      // all sizes 256-aligned
        void* p = ws + off;
        off += (bytes + 255) & ~(size_t)255;
        return p;
    };
    float*         cbuf  = (float*)alloc(147200000);          // conv buffer (full-T L1)
    unsigned char* spk1p = (unsigned char*)alloc(39936000);   // [1000,4,52,192]
    unsigned char* spk2p = (unsigned char*)alloc(21600000);   // [1000,8,27,100]
    unsigned char* spk3p = (unsigned char*)alloc(12960000);   // [1000,16,15,54]
    float*         d4    = (float*)alloc(41216);              // [64,161]  pre-act
    float*         d3    = (float*)alloc(76544);              // [32,598]
    float*         d2    = (float*)alloc(147200);             // [16,2300]
    float*         d1    = (float*)alloc(294400);             // [8,9200]
    float*         skip0 = (float*)alloc(2944000);            // [80,9200]
    float*         skip1 = (float*)alloc(1472000);            // [160,2300]
    float*         skip2 = (float*)alloc(765440);             // [320,598]
    float*         skip3 = (float*)alloc(412160);             // [640,161]
    float*         msS   = (float*)alloc(147200);             // scan scratch

    const int BS  = 256;
    const int SBS = 64;

    // 1) zero spikes + decoder accumulators (one contiguous span)
    {
        size_t nb = 39936000ull + 21600000 + 12960000
                  + 41216 + 76544 + 147200 + 294400;          // 75,055,360 B
        int n16 = (int)(nb / 16);
        k_zero16<<<CDIV(n16, BS), BS, 0, stream>>>((float4*)spk1p, n16);
    }

    // ---- encoder: 8 dispatches ----
    k_conv1<<<CDIV(1000 * 50 * 46, BS), BS, 0, stream>>>(x, w1, b1, cbuf);
    k_scan<<<CDIV(36800, SBS), SBS, 0, stream>>>(cbuf, spk1p, skip0, msS,
                                                 4, 9200, 184, 192, 52 * 192, 1);

    k_convs2<4, 8, 8, 4, 25, 92, 0, 52, 192>
        <<<dim3(CDIV(1000 * 25 * 23, BS), 1), BS, 0, stream>>>(spk1p, w2, b2, cbuf);
    k_scan<<<CDIV(18400, SBS), SBS, 0, stream>>>(cbuf, spk2p, skip1, msS,
                                                 8, 2300, 92, 100, 27 * 100, 1);

    k_convs2<8, 16, 16, 2, 13, 46, 1, 27, 100>
        <<<dim3(CDIV(1000 * 13 * 23, BS), 1), BS, 0, stream>>>(spk2p, w3, b3, cbuf);
    k_scan<<<CDIV(9568, SBS), SBS, 0, stream>>>(cbuf, spk3p, skip2, msS,
                                                16, 598, 46, 54, 15 * 54, 1);

    k_convs2<16, 32, 16, 2, 7, 23, 1, 15, 54>
        <<<dim3(CDIV(1000 * 7 * 12, BS), 2), BS, 0, stream>>>(spk3p, w4, b4, cbuf);
    k_scan<<<CDIV(5152, SBS), SBS, 0, stream>>>(cbuf, spk1p /*unused*/, skip3, msS,
                                                32, 161, 23, 31, 9 * 31, 0);

    // ---- decoder: 4 atomic split-K dispatches + final ----
    {   // L4: skip3[640,7,23] -> d4 (pre-act), CS=64, 10 chunks
        dim3 g(CDIV(161, 64), 64, 10);
        k_dec_conv0<<<g, 64, 0, stream>>>(skip3, 640, 7, 23, dw4, db4, d4, 64, 64);
    }
    {   // L3: [up(relu(d4)),64 | skip2,320] -> d3, CS=48, 8 chunks
        dim3 g(CDIV(598, 64), 32, 8);
        k_dec_conv<<<g, 64, 0, stream>>>(skip2, 320, d4, 64, 7, 23,
                                         dw3, db3, d3, 32, 48, 13, 46);
    }
    {   // L2: [up(relu(d3)),32 | skip1,160] -> d2, CS=48, 4 chunks
        dim3 g(CDIV(2300, 128), 16, 4);
        k_dec_conv<<<g, 128, 0, stream>>>(skip1, 160, d3, 32, 13, 46,
                                          dw2, db2, d2, 16, 48, 25, 92);
    }
    {   // L1: [up(relu(d2)),16 | skip0,80] -> d1, CS=48, 2 chunks
        dim3 g(CDIV(9200, BS), 8, 2);
        k_dec_conv<<<g, BS, 0, stream>>>(skip0, 80, d2, 16, 25, 92,
                                         dw1, db1, d1, 8, 48, 50, 184);
    }
    k_final<<<CDIV(36800, BS), BS, 0, stream>>>(d1, wo, bo, out);
}

// Round 9
// 833.997 us; speedup vs baseline: 1.2717x; 1.2717x over previous
//
#include <hip/hip_runtime.h>

#define KBINS  10
#define SBIN   100
#define BETA   0.9f
#define THR    1.0f
#define CDIV(a,b) (((a)+(b)-1)/(b))

// Padded spike layouts (halo zeros: 1 row top/bottom, 1 col left, 7 right):
//   spk1p [1000][ 4][52][192]   spk2p [1000][ 8][27][100]   spk3p [1000][16][15][54]

// ---------------------------------------------------------------------------
__global__ void k_zero16(float4* __restrict__ p, int n16) {
    int i = blockIdx.x * blockDim.x + threadIdx.x;
    if (i < n16) p[i] = make_float4(0.f, 0.f, 0.f, 0.f);
}

// ---------------------------------------------------------------------------
// Layer-1 conv, full T: 4 outputs (w) per thread, 4 couts.
// ---------------------------------------------------------------------------
__global__ void k_conv1(const float* __restrict__ x,
                        const float* __restrict__ w1,
                        const float* __restrict__ b1,
                        float* __restrict__ c1) {
    int n = blockIdx.x * blockDim.x + threadIdx.x;
    if (n >= 1000 * 50 * 46) return;
    int wq  = n % 46;
    int tmp = n / 46;
    int h   = tmp % 50;
    int t   = tmp / 50;
    int w0  = wq * 4;

    const float* xt = x + (size_t)t * 36800;
    float rm2 = (h  < 49)  ? 1.f : 0.f;
    float cm8 = (w0 < 180) ? 1.f : 0.f;
    int   r2  = min(2 * h + 2, 99);
    int   cb  = 2 * w0;
    int   c8  = min(cb + 8, 367);

    const float* row0 = xt + (2 * h) * 368 + cb;
    const float* row1 = row0 + 368;
    const float* row2 = xt + r2 * 368 + cb;

    float tap[3][9];
    #pragma unroll
    for (int j = 0; j < 8; j++) {
        tap[0][j] = row0[j];
        tap[1][j] = row1[j];
        tap[2][j] = row2[j] * rm2;
    }
    tap[0][8] = xt[(2 * h) * 368 + c8] * cm8;
    tap[1][8] = xt[(2 * h + 1) * 368 + c8] * cm8;
    tap[2][8] = xt[r2 * 368 + c8] * (rm2 * cm8);

    float* ot = c1 + (size_t)t * 36800 + h * 184 + w0;
    #pragma unroll
    for (int co = 0; co < 4; co++) {
        float b = b1[co];
        float a0 = b, a1 = b, a2 = b, a3 = b;
        #pragma unroll
        for (int r = 0; r < 3; r++) {
            #pragma unroll
            for (int kw = 0; kw < 3; kw++) {
                float wv = w1[co * 9 + r * 3 + kw];
                a0 = fmaf(tap[r][0 + kw], wv, a0);
                a1 = fmaf(tap[r][2 + kw], wv, a1);
                a2 = fmaf(tap[r][4 + kw], wv, a2);
                a3 = fmaf(tap[r][6 + kw], wv, a3);
            }
        }
        *(float4*)(ot + (size_t)co * 9200) = make_float4(a0, a1, a2, a3);
    }
}

// ---------------------------------------------------------------------------
// Membrane scan, full 1000 steps, PF=20 register double-buffer.
// ---------------------------------------------------------------------------
__global__ void k_scan(const float* __restrict__ cbuf,
                       unsigned char* __restrict__ spk,
                       float* __restrict__ skip,
                       float* __restrict__ mscratch,
                       int C, int HW, int Win, int Wp, int HpWp, int write_spk) {
    const int PF = 20;
    int CHW = C * HW;
    int p = blockIdx.x * blockDim.x + threadIdx.x;
    if (p >= CHW) return;
    int c  = p / HW;
    int hw = p - c * HW;
    int h  = hw / Win, w = hw - h * Win;

    const size_t tstr = (size_t)C * HpWp;
    unsigned char* sp = spk + (size_t)c * HpWp + (h + 1) * Wp + (w + 1);

    float m = 0.0f;
    float va[PF], vb[PF];
    #pragma unroll
    for (int j = 0; j < PF; j++) va[j] = cbuf[(size_t)j * CHW + p];

    const int T = KBINS * SBIN;
    for (int k = 0; k < KBINS; k++) {
        float s = 0.0f, q = 0.0f;
        for (int b = 0; b < SBIN / PF; b++) {
            int t0 = k * SBIN + b * PF;
            int tn = t0 + PF;
            bool more = (tn < T);
            #pragma unroll
            for (int j = 0; j < PF; j++)
                vb[j] = more ? cbuf[(size_t)(tn + j) * CHW + p] : 0.0f;
            #pragma unroll
            for (int j = 0; j < PF; j++) {
                m = fmaf(m, BETA, va[j]);
                float spv = (m - THR > 0.0f) ? 1.0f : 0.0f;
                m -= spv * THR;
                if (write_spk) sp[(size_t)(t0 + j) * tstr] = (unsigned char)spv;
                s += m;
                q = fmaf(m, m, q);
            }
            #pragma unroll
            for (int j = 0; j < PF; j++) va[j] = vb[j];
        }
        float mean = s * (1.0f / SBIN);
        float var  = q * (1.0f / SBIN) - mean * mean;
        float sd   = sqrtf(fmaxf(var, 1e-8f));
        skip[(size_t)(k * 2 * C + c) * HW + hw]     = mean;
        skip[(size_t)(k * 2 * C + C + c) * HW + hw] = sd;
    }
    mscratch[p] = m;
}

// ---------------------------------------------------------------------------
// Stride-2 time-conv from padded u8 spikes, OW outputs/thread, COG couts.
// ---------------------------------------------------------------------------
template<int CIN, int COUT, int COG, int OW,
         int HOUT, int WOUT, int PADH, int HP, int WP>
__global__ void k_convs2(const unsigned char* __restrict__ spk,
                         const float* __restrict__ wt,
                         const float* __restrict__ bias,
                         float* __restrict__ out) {
    const int WQ = (WOUT + OW - 1) / OW;
    const int NT = 2 * OW + 1;
    int n = blockIdx.x * blockDim.x + threadIdx.x;
    if (n >= 1000 * HOUT * WQ) return;
    int wq  = n % WQ;
    int tmp = n / WQ;
    int h   = tmp % HOUT;
    int t   = tmp / HOUT;
    int cog = blockIdx.y;
    int w0  = wq * OW;

    const unsigned char* base = spk + (size_t)t * CIN * HP * WP
                              + (2 * h - PADH + 1) * WP + (2 * w0 + 1);

    float acc[OW][COG];
    #pragma unroll
    for (int q = 0; q < OW; q++)
        #pragma unroll
        for (int co = 0; co < COG; co++) acc[q][co] = bias[cog * COG + co];

    for (int ci = 0; ci < CIN; ci++) {
        const unsigned char* ic = base + (size_t)ci * HP * WP;
        float tap[3][NT];
        #pragma unroll
        for (int r = 0; r < 3; r++)
            #pragma unroll
            for (int j = 0; j < NT; j++)
                tap[r][j] = (float)ic[r * WP + j];
        #pragma unroll
        for (int co = 0; co < COG; co++) {
            const float* wc = wt + ((size_t)(cog * COG + co) * CIN + ci) * 9;
            #pragma unroll
            for (int r = 0; r < 3; r++)
                #pragma unroll
                for (int kw = 0; kw < 3; kw++) {
                    float wv = wc[r * 3 + kw];
                    #pragma unroll
                    for (int q = 0; q < OW; q++)
                        acc[q][co] = fmaf(tap[r][2 * q + kw], wv, acc[q][co]);
                }
        }
    }

    float* ot = out + ((size_t)t * COUT + cog * COG) * (HOUT * WOUT) + h * WOUT + w0;
    #pragma unroll
    for (int co = 0; co < COG; co++) {
        float* oc = ot + (size_t)co * (HOUT * WOUT);
        if constexpr (OW == 4) {
            *(float4*)oc = make_float4(acc[0][co], acc[1][co], acc[2][co], acc[3][co]);
        } else {
            if (w0 + 2 <= WOUT) *(float2*)oc = make_float2(acc[0][co], acc[1][co]);
            else                oc[0] = acc[0][co];
        }
    }
}

// ---------------------------------------------------------------------------
// Bilinear upsample (JAX half-pixel, edge-clamp) + channel concat (R3-proven).
// d inputs are post-ReLU.
// ---------------------------------------------------------------------------
__global__ void k_up_cat(const float* __restrict__ up_src, int Cup, int Hi, int Wi,
                         const float* __restrict__ skip, int Cskip,
                         float* __restrict__ out, int Ho, int Wo) {
    int total = (Cup + Cskip) * Ho * Wo;
    int n = blockIdx.x * blockDim.x + threadIdx.x;
    if (n >= total) return;
    int w   = n % Wo;
    int tmp = n / Wo;
    int h   = tmp % Ho;
    int c   = tmp / Ho;
    float v;
    if (c < Cup) {
        float ph = (h + 0.5f) * (float)Hi / (float)Ho - 0.5f;
        float pw = (w + 0.5f) * (float)Wi / (float)Wo - 0.5f;
        float fh = floorf(ph), fw = floorf(pw);
        int h0 = (int)fh, w0 = (int)fw;
        float ah = ph - fh, aw = pw - fw;
        int h0c = min(max(h0, 0), Hi - 1), h1c = min(max(h0 + 1, 0), Hi - 1);
        int w0c = min(max(w0, 0), Wi - 1), w1c = min(max(w0 + 1, 0), Wi - 1);
        const float* sc = up_src + (size_t)c * Hi * Wi;
        float v00 = sc[h0c * Wi + w0c], v01 = sc[h0c * Wi + w1c];
        float v10 = sc[h1c * Wi + w0c], v11 = sc[h1c * Wi + w1c];
        v = (1.0f - ah) * ((1.0f - aw) * v00 + aw * v01)
          + ah * ((1.0f - aw) * v10 + aw * v11);
    } else {
        v = skip[(size_t)(c - Cup) * Ho * Wo + h * Wo + w];
    }
    out[n] = v;
}

// ---------------------------------------------------------------------------
// Decoder split-K conv, TEMPLATED: CS channels/chunk (compile-time unroll),
// COG couts/thread (taps loaded once serve COG outputs). part[chunk][Cout][HW].
// ---------------------------------------------------------------------------
template<int CIN, int CS, int COG>
__global__ void k_dconv(const float* __restrict__ in,
                        const float* __restrict__ wt,
                        float* __restrict__ part,
                        int Cout, int H, int W) {
    int HW  = H * W;
    int pix = blockIdx.x * blockDim.x + threadIdx.x;
    if (pix >= HW) return;
    int co0   = blockIdx.y * COG;
    int chunk = blockIdx.z;
    int h = pix / W, w = pix - h * W;

    int off[9]; float msk[9];
    #pragma unroll
    for (int kh = 0; kh < 3; kh++) {
        int r = h + kh - 1;
        bool rok = (r >= 0) && (r < H);
        int rc = rok ? r : 0;
        #pragma unroll
        for (int kw = 0; kw < 3; kw++) {
            int cc = w + kw - 1;
            bool cok = (cc >= 0) && (cc < W);
            int ccc = cok ? cc : 0;
            off[kh * 3 + kw] = rc * W + ccc;
            msk[kh * 3 + kw] = (rok && cok) ? 1.0f : 0.0f;
        }
    }

    const float* ibase = in + (size_t)chunk * CS * HW;
    const float* wbase = wt + ((size_t)co0 * CIN + (size_t)chunk * CS) * 9;

    float acc[COG];
    #pragma unroll
    for (int co = 0; co < COG; co++) acc[co] = 0.0f;

    #pragma unroll 8
    for (int ci = 0; ci < CS; ci++) {
        const float* ic = ibase + (size_t)ci * HW;
        float tap[9];
        #pragma unroll
        for (int j = 0; j < 9; j++)
            tap[j] = msk[j] * ic[off[j]];
        #pragma unroll
        for (int co = 0; co < COG; co++) {
            const float* wc = wbase + ((size_t)co * CIN + ci) * 9;
            #pragma unroll
            for (int j = 0; j < 9; j++)
                acc[co] = fmaf(tap[j], wc[j], acc[co]);
        }
    }

    float* pp = part + ((size_t)chunk * Cout + co0) * HW + pix;
    #pragma unroll
    for (int co = 0; co < COG; co++) pp[(size_t)co * HW] = acc[co];
}

__global__ void k_reduce_relu(const float* __restrict__ part,
                              const float* __restrict__ bias,
                              float* __restrict__ out,
                              int Cout, int HW, int nchunks) {
    int n = blockIdx.x * blockDim.x + threadIdx.x;
    if (n >= Cout * HW) return;
    int co = n / HW;
    float acc = bias[co];
    for (int c = 0; c < nchunks; c++)
        acc += part[(size_t)c * Cout * HW + n];
    out[n] = fmaxf(acc, 0.0f);
}

// ---------------------------------------------------------------------------
// Final: bilinear up d1 (post-ReLU) [8,50,184] -> (100,368), fused 1x1 conv.
// ---------------------------------------------------------------------------
__global__ void k_final(const float* __restrict__ d1,
                        const float* __restrict__ wo,
                        const float* __restrict__ bo,
                        float* __restrict__ out) {
    int n = blockIdx.x * blockDim.x + threadIdx.x;
    if (n >= 36800) return;
    int w = n % 368, h = n / 368;
    float ph = (h + 0.5f) * 0.5f - 0.5f;
    float pw = (w + 0.5f) * 0.5f - 0.5f;
    float fh = floorf(ph), fw = floorf(pw);
    int h0 = (int)fh, w0 = (int)fw;
    float ah = ph - fh, aw = pw - fw;
    int h0c = min(max(h0, 0), 49),  h1c = min(max(h0 + 1, 0), 49);
    int w0c = min(max(w0, 0), 183), w1c = min(max(w0 + 1, 0), 183);
    float acc = bo[0];
    #pragma unroll
    for (int c = 0; c < 8; c++) {
        const float* sc = d1 + c * 9200;
        float v00 = sc[h0c * 184 + w0c], v01 = sc[h0c * 184 + w1c];
        float v10 = sc[h1c * 184 + w0c], v11 = sc[h1c * 184 + w1c];
        float v = (1.0f - ah) * ((1.0f - aw) * v00 + aw * v01)
                + ah * ((1.0f - aw) * v10 + aw * v11);
        acc = fmaf(wo[c], v, acc);
    }
    out[n] = acc;
}

// ---------------------------------------------------------------------------
extern "C" void kernel_launch(void* const* d_in, const int* in_sizes, int n_in,
                              void* d_out, int out_size, void* d_ws, size_t ws_size,
                              hipStream_t stream) {
    (void)in_sizes; (void)n_in; (void)out_size; (void)ws_size;
    const float* x   = (const float*)d_in[0];
    const float* w1  = (const float*)d_in[1];
    const float* b1  = (const float*)d_in[2];
    const float* w2  = (const float*)d_in[3];
    const float* b2  = (const float*)d_in[4];
    const float* w3  = (const float*)d_in[5];
    const float* b3  = (const float*)d_in[6];
    const float* w4  = (const float*)d_in[7];
    const float* b4  = (const float*)d_in[8];
    const float* dw4 = (const float*)d_in[9];
    const float* db4 = (const float*)d_in[10];
    const float* dw3 = (const float*)d_in[11];
    const float* db3 = (const float*)d_in[12];
    const float* dw2 = (const float*)d_in[13];
    const float* db2 = (const float*)d_in[14];
    const float* dw1 = (const float*)d_in[15];
    const float* db1 = (const float*)d_in[16];
    const float* wo  = (const float*)d_in[17];
    const float* bo  = (const float*)d_in[18];
    float* out = (float*)d_out;

    // ---- workspace ----
    char* ws = (char*)d_ws;
    size_t off = 0;
    auto alloc = [&](size_t bytes) -> void* {
        void* p = ws + off;
        off += (bytes + 255) & ~(size_t)255;
        return p;
    };
    float*         cbuf  = (float*)alloc(147200000);          // conv buffer
    unsigned char* spk1p = (unsigned char*)alloc(39936000);   // [1000,4,52,192]
    unsigned char* spk2p = (unsigned char*)alloc(21600000);   // [1000,8,27,100]
    unsigned char* spk3p = (unsigned char*)alloc(12960000);   // [1000,16,15,54]
    float*         skip0 = (float*)alloc(2944000);            // [80,9200]
    float*         skip1 = (float*)alloc(1472000);            // [160,2300]
    float*         skip2 = (float*)alloc(765440);             // [320,598]
    float*         skip3 = (float*)alloc(412160);             // [640,161]
    float*         msS   = (float*)alloc(147200);             // scan scratch
    // decoder buffers alias cbuf (dead after encoder)
    char* dec = (char*)cbuf;
    size_t doff = 0;
    auto dalloc = [&](size_t bytes) -> void* {
        void* p = dec + doff;
        doff += (bytes + 255) & ~(size_t)255;
        return p;
    };
    float* d4   = (float*)dalloc(10304u * 4);                 // [64,161] post-ReLU
    float* d3   = (float*)dalloc(19136u * 4);                 // [32,598]
    float* d2   = (float*)dalloc(36800u * 4);                 // [16,2300]
    float* d1   = (float*)dalloc(73600u * 4);                 // [8,9200]
    float* cat3 = (float*)dalloc(229632u * 4);                // [384,598]
    float* cat2 = (float*)dalloc(441600u * 4);                // [192,2300]
    float* cat1 = (float*)dalloc(883200u * 4);                // [96,9200]
    float* part = (float*)dalloc(230400u * 4);                // split-K partials

    const int BS  = 256;
    const int SBS = 64;

    // zero spike halos (contiguous span)
    {
        size_t nb = 39936000ull + 21600000 + 12960000;
        int n16 = (int)(nb / 16);
        k_zero16<<<CDIV(n16, BS), BS, 0, stream>>>((float4*)spk1p, n16);
    }

    // ---- encoder (unchanged from R7) ----
    k_conv1<<<CDIV(1000 * 50 * 46, BS), BS, 0, stream>>>(x, w1, b1, cbuf);
    k_scan<<<CDIV(36800, SBS), SBS, 0, stream>>>(cbuf, spk1p, skip0, msS,
                                                 4, 9200, 184, 192, 52 * 192, 1);

    k_convs2<4, 8, 8, 4, 25, 92, 0, 52, 192>
        <<<dim3(CDIV(1000 * 25 * 23, BS), 1), BS, 0, stream>>>(spk1p, w2, b2, cbuf);
    k_scan<<<CDIV(18400, SBS), SBS, 0, stream>>>(cbuf, spk2p, skip1, msS,
                                                 8, 2300, 92, 100, 27 * 100, 1);

    k_convs2<8, 16, 16, 2, 13, 46, 1, 27, 100>
        <<<dim3(CDIV(1000 * 13 * 23, BS), 1), BS, 0, stream>>>(spk2p, w3, b3, cbuf);
    k_scan<<<CDIV(9568, SBS), SBS, 0, stream>>>(cbuf, spk3p, skip2, msS,
                                                16, 598, 46, 54, 15 * 54, 1);

    k_convs2<16, 32, 16, 2, 7, 23, 1, 15, 54>
        <<<dim3(CDIV(1000 * 7 * 12, BS), 2), BS, 0, stream>>>(spk3p, w4, b4, cbuf);
    k_scan<<<CDIV(5152, SBS), SBS, 0, stream>>>(cbuf, spk1p /*unused*/, skip3, msS,
                                                32, 161, 23, 31, 9 * 31, 0);

    // ---- decoder: up_cat + templated split-K conv + reduce ----
    {   // L4: skip3[640,7,23] -> d4[64,161]; CS=32 (20 chunks), COG=4
        dim3 g(CDIV(161, 64), 16, 20);
        k_dconv<640, 32, 4><<<g, 64, 0, stream>>>(skip3, dw4, part, 64, 7, 23);
        k_reduce_relu<<<CDIV(64 * 161, BS), BS, 0, stream>>>(part, db4, d4, 64, 161, 20);
    }
    {   // L3: cat3=[up(d4),64|skip2,320] -> d3[32,598]; CS=32 (12), COG=4
        k_up_cat<<<CDIV(384 * 598, BS), BS, 0, stream>>>(d4, 64, 7, 23,
                                                         skip2, 320, cat3, 13, 46);
        dim3 g(CDIV(598, 64), 8, 12);
        k_dconv<384, 32, 4><<<g, 64, 0, stream>>>(cat3, dw3, part, 32, 13, 46);
        k_reduce_relu<<<CDIV(32 * 598, BS), BS, 0, stream>>>(part, db3, d3, 32, 598, 12);
    }
    {   // L2: cat2=[up(d3),32|skip1,160] -> d2[16,2300]; CS=32 (6), COG=4
        k_up_cat<<<CDIV(192 * 2300, BS), BS, 0, stream>>>(d3, 32, 13, 46,
                                                          skip1, 160, cat2, 25, 92);
        dim3 g(CDIV(2300, 128), 4, 6);
        k_dconv<192, 32, 4><<<g, 128, 0, stream>>>(cat2, dw2, part, 16, 25, 92);
        k_reduce_relu<<<CDIV(16 * 2300, BS), BS, 0, stream>>>(part, db2, d2, 16, 2300, 6);
    }
    {   // L1: cat1=[up(d2),16|skip0,80] -> d1[8,9200]; CS=32 (3), COG=4
        k_up_cat<<<CDIV(96 * 9200, BS), BS, 0, stream>>>(d2, 16, 25, 92,
                                                         skip0, 80, cat1, 50, 184);
        dim3 g(CDIV(9200, BS), 2, 3);
        k_dconv<96, 32, 4><<<g, BS, 0, stream>>>(cat1, dw1, part, 8, 50, 184);
        k_reduce_relu<<<CDIV(8 * 9200, BS), BS, 0, stream>>>(part, db1, d1, 8, 9200, 3);
    }
    k_final<<<CDIV(36800, BS), BS, 0, stream>>>(d1, wo, bo, out);
}